// Round 4
// baseline (8833.840 us; speedup 1.0000x reference)
//
#include <hip/hip_runtime.h>
#include <hip/hip_bf16.h>
#include <math.h>

#define B_  64
#define T_  1024
#define H_  256
#define K_  64
#define U_  128
#define U3_ 384

typedef unsigned short ushort_t;

__device__ __forceinline__ float bf2f(ushort_t v) {
  unsigned int u = ((unsigned int)v) << 16;
  return __builtin_bit_cast(float, u);
}
__device__ __forceinline__ ushort_t f2bf(float f) {
  unsigned int u = __builtin_bit_cast(unsigned int, f);
  unsigned int lsb = (u >> 16) & 1u;
  u += 0x7fffu + lsb;
  return (ushort_t)(u >> 16);
}
// load element i from a buffer that is f32 (isf=1) or bf16 (isf=0)
__device__ __forceinline__ float ldf(const void* p, size_t i, int isf) {
  return isf ? ((const float*)p)[i] : bf2f(((const ushort_t*)p)[i]);
}

// ------------------------------------------------ dtype sniff: flag=1 if inputs are f32
__global__ void k_sniff(const ushort_t* __restrict__ xr, int* __restrict__ flag) {
  __shared__ int red[256];
  int tx = threadIdx.x;
  int hits = 0;
  for (int i = 0; i < 64; ++i) {
    ushort_t w = xr[tx + i * 256];
    int e = (w >> 7) & 0xff;
    hits += (e >= 0x70 && e <= 0x82) ? 1 : 0;
  }
  red[tx] = hits;
  __syncthreads();
  for (int off = 128; off > 0; off >>= 1) {
    if (tx < off) red[tx] += red[tx + off];
    __syncthreads();
  }
  if (tx == 0) flag[0] = (red[0] < 12288) ? 1 : 0;  // <75% plausible-bf16 => f32
}

// ------------------------------------------------ init m state
__global__ void k_init_m(const void* __restrict__ m0a, const void* __restrict__ m0o,
                         const int* __restrict__ flag,
                         float* __restrict__ ma_ws, float* __restrict__ mo_ws) {
  int b = blockIdx.x, tx = threadIdx.x, isf = *flag;
  ma_ws[b * H_ + tx] = ldf(m0a, tx, isf);
  mo_ws[b * H_ + tx] = ldf(m0o, tx, isf);
}

// ------------------------------------------------ Wtf[g][j][u] = W_g[u][j]  (f32 out)
__global__ void k_transpose(const void* __restrict__ Wa, const void* __restrict__ Wo,
                            const int* __restrict__ flag, float* __restrict__ Wtf) {
  int bx = blockIdx.x, isf = *flag;
  int g = bx / 192;
  int i = (bx % 192) * 256 + threadIdx.x;  // i = j*128 + u
  const void* W = g ? Wo : Wa;
  int jj = i >> 7, u = i & 127;
  Wtf[(size_t)g * (U3_ * U_) + i] = ldf(W, u * U3_ + jj, isf);
}

// ------------------------------------------------ Phase A: P[b, g*64+k, h] = sum_j U[k,h,j] m[b,j]  (f32 out)
__global__ __launch_bounds__(256) void k_phaseA(
    const void* __restrict__ Ua, const void* __restrict__ Va,
    const void* __restrict__ Uo, const void* __restrict__ Vo,
    const int* __restrict__ flag,
    const float* __restrict__ ma_ws, const float* __restrict__ mo_ws,
    float* __restrict__ Pf) {
  int gk = blockIdx.x;
  int g = gk >> 6, k = gk & 63;
  const void* U = (g == 0) ? Ua : (g == 1) ? Va : (g == 2) ? Uo : Vo;
  const float* msrc = (g & 1) ? mo_ws : ma_ws;  // Ua(ma), Va(mo), Uo(ma), Vo(mo)
  int tx = threadIdx.x;  // h
  int isf = *flag;
  __shared__ __align__(16) float m_l[64 * 128];
  float acc[64];
#pragma unroll
  for (int b = 0; b < 64; ++b) acc[b] = 0.f;
  size_t rowoff = ((size_t)k * H_ + tx) * H_;
  for (int pass = 0; pass < 2; ++pass) {
    for (int i = 0; i < 32; ++i) {
      int flat = tx + i * 256;
      m_l[flat] = msrc[(flat >> 7) * H_ + pass * 128 + (flat & 127)];
    }
    __syncthreads();
    for (int c = 0; c < 16; ++c) {
      float uv[8];
      if (isf) {
        const float* uf = (const float*)U + rowoff + pass * 128 + c * 8;
        float4 A = *(const float4*)uf;
        float4 Bv = *(const float4*)(uf + 4);
        uv[0] = A.x; uv[1] = A.y; uv[2] = A.z; uv[3] = A.w;
        uv[4] = Bv.x; uv[5] = Bv.y; uv[6] = Bv.z; uv[7] = Bv.w;
      } else {
        const ushort_t* ub = (const ushort_t*)U + rowoff + pass * 128 + c * 8;
        uint4 raw = *(const uint4*)ub;
        uv[0] = bf2f((ushort_t)(raw.x & 0xffff)); uv[1] = bf2f((ushort_t)(raw.x >> 16));
        uv[2] = bf2f((ushort_t)(raw.y & 0xffff)); uv[3] = bf2f((ushort_t)(raw.y >> 16));
        uv[4] = bf2f((ushort_t)(raw.z & 0xffff)); uv[5] = bf2f((ushort_t)(raw.z >> 16));
        uv[6] = bf2f((ushort_t)(raw.w & 0xffff)); uv[7] = bf2f((ushort_t)(raw.w >> 16));
      }
#pragma unroll
      for (int b = 0; b < 64; ++b) {
        const float* mr = &m_l[b * 128 + c * 8];
        float4 mA = *(const float4*)mr;
        float4 mB = *(const float4*)(mr + 4);
        float s = acc[b];
        s = fmaf(uv[0], mA.x, s); s = fmaf(uv[1], mA.y, s);
        s = fmaf(uv[2], mA.z, s); s = fmaf(uv[3], mA.w, s);
        s = fmaf(uv[4], mB.x, s); s = fmaf(uv[5], mB.y, s);
        s = fmaf(uv[6], mB.z, s); s = fmaf(uv[7], mB.w, s);
        acc[b] = s;
      }
    }
    __syncthreads();
  }
  size_t base = ((size_t)(g * 64 + k)) * H_ + tx;
#pragma unroll 4
  for (int b = 0; b < 64; ++b) Pf[base + (size_t)b * (256 * H_)] = acc[b];
}

// ------------------------------------------------ Phase B (VALU): tanh(x[b,t,:]·P[b,n,:]) -> aspect/opinion (bf16)
__global__ __launch_bounds__(256) void k_phaseB_valu(
    const void* __restrict__ x, const int* __restrict__ flag,
    const float* __restrict__ Pf,
    ushort_t* __restrict__ aspect, ushort_t* __restrict__ opinion) {
  int b = blockIdx.x >> 2;
  int nq = blockIdx.x & 3;
  int tid = threadIdx.x;
  int isf = *flag;
  __shared__ __align__(8) float Pl[64 * 258];
  __shared__ float xl[4][256];
  for (int i = 0; i < 64; ++i) {
    int flat = tid + i * 256;
    int r = flat >> 8, h = flat & 255;
    Pl[r * 258 + h] = Pf[((size_t)b * 256 + nq * 64 + r) * 256 + h];
  }
  __syncthreads();
  int tp = tid >> 6, nl = tid & 63;
  int n = nq * 64 + nl;
  ushort_t* dst;
  int nn;
  if (n < 128) { dst = aspect; nn = n; } else { dst = opinion; nn = n - 128; }
  const float2* prow = (const float2*)(Pl + nl * 258);
  for (int tc = 0; tc < 256; ++tc) {
#pragma unroll
    for (int i = 0; i < 4; ++i) {
      int flat = tid + i * 256;
      int tr = flat >> 8, h = flat & 255;
      xl[tr][h] = ldf(x, ((size_t)b * T_ + tc * 4 + tr) * H_ + h, isf);
    }
    __syncthreads();
    float acc = 0.f;
    const float* xrow = xl[tp];
#pragma unroll 4
    for (int c = 0; c < 128; ++c) {
      float2 p2 = prow[c];
      acc = fmaf(xrow[2 * c], p2.x, acc);
      acc = fmaf(xrow[2 * c + 1], p2.y, acc);
    }
    int t = tc * 4 + tp;
    dst[((size_t)b * T_ + t) * U_ + nn] = f2bf(tanhf(acc));
    __syncthreads();
  }
}

// ------------------------------------------------ Phase C (VALU): xw[row,col] = seq[row,:]·Wt[col,:]
// z|r cols (0..255) -> bf16 zr buffer; h cols (256..383) -> f32 xh buffer
__global__ __launch_bounds__(192) void k_phaseC_valu(
    const ushort_t* __restrict__ aspect, const ushort_t* __restrict__ opinion,
    const float* __restrict__ Wtf,
    ushort_t* __restrict__ zr_a, ushort_t* __restrict__ zr_o,
    float* __restrict__ xh_a, float* __restrict__ xh_o) {
  int bx = blockIdx.x;
  int g = bx >> 9, ch = (bx >> 8) & 1, rc = bx & 255;
  const ushort_t* A = g ? opinion : aspect;
  ushort_t* ZR = g ? zr_o : zr_a;
  float* XH = g ? xh_o : xh_a;
  int tid = threadIdx.x;
  int col = ch * 192 + tid;
  __shared__ __align__(8) float Wl[192 * 130];
  __shared__ float sl[128];
  for (int i = 0; i < 128; ++i) {
    int flat = tid + i * 192;
    int r = flat >> 7, u = flat & 127;
    Wl[r * 130 + u] = Wtf[(size_t)g * (U3_ * U_) + (ch * 192 + r) * 128 + u];
  }
  __syncthreads();
  const float2* wrow = (const float2*)(Wl + tid * 130);
  for (int rr = 0; rr < 256; ++rr) {
    int row = rc * 256 + rr;
    if (tid < 128) sl[tid] = bf2f(A[(size_t)row * U_ + tid]);
    __syncthreads();
    float acc = 0.f;
#pragma unroll 4
    for (int c = 0; c < 64; ++c) {
      float2 w2 = wrow[c];
      acc = fmaf(sl[2 * c], w2.x, acc);
      acc = fmaf(sl[2 * c + 1], w2.y, acc);
    }
    if (col < 256) ZR[(size_t)row * 256 + col] = f2bf(acc);
    else           XH[(size_t)row * U_ + (col - 256)] = acc;
    __syncthreads();
  }
}

// ------------------------------------------------ GRU scan (out: f32)
__global__ __launch_bounds__(384) void k_scan(const ushort_t* __restrict__ zr_a,
                                              const ushort_t* __restrict__ zr_o,
                                              const float* __restrict__ xh_a,
                                              const float* __restrict__ xh_o,
                                              const void* __restrict__ Ra,
                                              const void* __restrict__ Ro,
                                              const int* __restrict__ flag,
                                              float* __restrict__ out, int layer) {
  int g = blockIdx.x >> 6;
  int b = blockIdx.x & 63;
  const ushort_t* zr = (g ? zr_o : zr_a) + (size_t)b * T_ * 256;
  const float* xh = (g ? xh_o : xh_a) + (size_t)b * T_ * U_;
  const void* R = g ? Ro : Ra;
  float* op = out + ((size_t)g * B_ * T_ + (size_t)b * T_) * U_;
  int j = threadIdx.x;
  float r_reg[128];
  if (*flag) {
    const float* Rf = (const float*)R;
#pragma unroll
    for (int u = 0; u < 128; ++u) r_reg[u] = Rf[u * U3_ + j];
  } else {
    const ushort_t* Rb = (const ushort_t*)R;
#pragma unroll
    for (int u = 0; u < 128; ++u) r_reg[u] = bf2f(Rb[u * U3_ + j]);
  }
  __shared__ __align__(16) float h_lds[128];
  __shared__ float pre[384];
  if (j < U_) h_lds[j] = 0.f;
  __syncthreads();
  for (int t = 0; t < T_; ++t) {
    float xz = 0.f, xr = 0.f, xhv = 0.f, oldo = 0.f;
    if (j < U_) {
      xz = bf2f(zr[t * 256 + j]);
      xr = bf2f(zr[t * 256 + 128 + j]);
      xhv = xh[t * U_ + j];
      if (layer) oldo = op[(size_t)t * U_ + j];
    }
    float a0 = 0.f, a1 = 0.f, a2 = 0.f, a3 = 0.f;
#pragma unroll
    for (int c = 0; c < 32; ++c) {
      float4 h4 = ((const float4*)h_lds)[c];
      a0 = fmaf(h4.x, r_reg[4 * c + 0], a0);
      a1 = fmaf(h4.y, r_reg[4 * c + 1], a1);
      a2 = fmaf(h4.z, r_reg[4 * c + 2], a2);
      a3 = fmaf(h4.w, r_reg[4 * c + 3], a3);
    }
    pre[j] = (a0 + a1) + (a2 + a3);
    __syncthreads();
    if (j < U_) {
      float z = 1.f / (1.f + __expf(-(xz + pre[j])));
      float r = 1.f / (1.f + __expf(-(xr + pre[j + U_])));
      float hh = tanhf(fmaf(r, pre[j + 2 * U_], xhv));
      float hn = z * h_lds[j] + (1.f - z) * hh;
      op[(size_t)t * U_ + j] = layer ? (oldo + hn) : hn;
      h_lds[j] = hn;
    }
    __syncthreads();
  }
}

// ------------------------------------------------ scores[g,b,t] = ra[b,t,:]·v
__global__ void k_score(const float* __restrict__ out, const void* __restrict__ va,
                        const void* __restrict__ vo, const int* __restrict__ flag,
                        float* __restrict__ scores) {
  int wave = threadIdx.x >> 6, lane = threadIdx.x & 63;
  int pair = blockIdx.x * 4 + wave;  // [0, 131072)
  int g = pair >> 16;
  int bt = pair & 65535;
  int isf = *flag;
  const void* v = g ? vo : va;
  const float* o = out + ((size_t)g * (B_ * T_) + bt) * U_ + lane * 2;
  float s = o[0] * ldf(v, lane * 2, isf) + o[1] * ldf(v, lane * 2 + 1, isf);
#pragma unroll
  for (int off = 32; off > 0; off >>= 1) s += __shfl_down(s, off, 64);
  if (lane == 0) scores[pair] = s;
}

// ------------------------------------------------ softmax over T, in place
__global__ void k_softmax(float* __restrict__ scores) {
  int row = blockIdx.x;
  float* s = scores + (size_t)row * T_;
  int tx = threadIdx.x;
  __shared__ float red[256];
  float v[4];
  float mx = -1e30f;
#pragma unroll
  for (int i = 0; i < 4; ++i) { v[i] = s[tx + i * 256]; mx = fmaxf(mx, v[i]); }
  red[tx] = mx;
  __syncthreads();
  for (int off = 128; off > 0; off >>= 1) {
    if (tx < off) red[tx] = fmaxf(red[tx], red[tx + off]);
    __syncthreads();
  }
  float M = red[0];
  __syncthreads();
  float sm = 0.f;
#pragma unroll
  for (int i = 0; i < 4; ++i) { v[i] = expf(v[i] - M); sm += v[i]; }
  red[tx] = sm;
  __syncthreads();
  for (int off = 128; off > 0; off >>= 1) {
    if (tx < off) red[tx] += red[tx + off];
    __syncthreads();
  }
  float inv = 1.f / red[0];
#pragma unroll
  for (int i = 0; i < 4; ++i) s[tx + i * 256] = v[i] * inv;
}

// ------------------------------------------------ m = tanh(m@M) + alpha^T x
__global__ void k_ctx_m(const float* __restrict__ alpha, const void* __restrict__ x,
                        const void* __restrict__ Ma, const void* __restrict__ Mo,
                        const int* __restrict__ flag,
                        float* __restrict__ ma_ws, float* __restrict__ mo_ws) {
  int g = blockIdx.x >> 6, b = blockIdx.x & 63;
  int isf = *flag;
  const float* al = alpha + ((size_t)g * B_ + b) * T_;
  const void* Mm = g ? Mo : Ma;
  float* m_ws = g ? mo_ws : ma_ws;
  int tx = threadIdx.x;  // h
  __shared__ float a_l[1024];
  __shared__ float m_l[256];
#pragma unroll
  for (int i = 0; i < 4; ++i) a_l[tx + i * 256] = al[tx + i * 256];
  m_l[tx] = m_ws[b * H_ + tx];
  __syncthreads();
  float acc = 0.f;
  for (int t = 0; t < T_; ++t)
    acc = fmaf(a_l[t], ldf(x, (size_t)(b * T_ + t) * H_ + tx, isf), acc);
  float acc2 = 0.f;
  for (int jj = 0; jj < 256; ++jj) acc2 = fmaf(m_l[jj], ldf(Mm, jj * 256 + tx, isf), acc2);
  m_ws[b * H_ + tx] = tanhf(acc2) + acc;
}

// ------------------------------------------------ launch
extern "C" void kernel_launch(void* const* d_in, const int* in_sizes, int n_in,
                              void* d_out, int out_size, void* d_ws, size_t ws_size,
                              hipStream_t stream) {
  const void* x_r = d_in[0];
  const void* m0a = d_in[1];
  const void* m0o = d_in[2];
  const void* Ua  = d_in[3];
  const void* Uo  = d_in[4];
  const void* Va  = d_in[5];
  const void* Vo  = d_in[6];
  const void* Ma  = d_in[7];
  const void* Mo  = d_in[8];
  const void* va  = d_in[9];
  const void* vo  = d_in[10];
  const void* Wa  = d_in[11];
  const void* Ra  = d_in[12];
  const void* Wo  = d_in[13];
  const void* Ro  = d_in[14];
  float* out = (float*)d_out;  // reference output dtype = float32

  char* ws = (char*)d_ws;
  int*      flag    = (int*)(ws + 0);               // 1 KB pad
  float*    ma_ws   = (float*)(ws + 1024);          // 64 KB
  float*    mo_ws   = (float*)(ws + 66560);         // 64 KB
  float*    Wtf     = (float*)(ws + 132096);        // 384 KB [2,384,128] f32
  float*    Pf      = (float*)(ws + 525312);        // 16 MB  [64,256,256] f32
  float*    scores  = (float*)(ws + 525312);        // ALIAS: Pf dead when scores live
  ushort_t* aspect  = (ushort_t*)(ws + 17302528);   // 16 MB  bf16
  ushort_t* opinion = (ushort_t*)(ws + 34079744);   // 16 MB
  ushort_t* zr_a    = (ushort_t*)(ws + 50856960);   // 32 MB  [64,1024,256] bf16
  ushort_t* zr_o    = (ushort_t*)(ws + 84411392);   // 32 MB
  float*    xh_a    = (float*)(ws + 117965824);     // 32 MB  [64,1024,128] f32
  float*    xh_o    = (float*)(ws + 151520256);     // 32 MB -> total 185,074,688 B

  if (ws_size < 185074688ULL) return;  // tripwire: zero output (err ~1.96) => ws too small

  k_sniff<<<dim3(1), dim3(256), 0, stream>>>((const ushort_t*)x_r, flag);
  k_init_m<<<dim3(64), dim3(256), 0, stream>>>(m0a, m0o, flag, ma_ws, mo_ws);
  k_transpose<<<dim3(384), dim3(256), 0, stream>>>(Wa, Wo, flag, Wtf);

  for (int layer = 0; layer < 2; ++layer) {
    k_phaseA<<<dim3(256), dim3(256), 0, stream>>>(Ua, Va, Uo, Vo, flag, ma_ws, mo_ws, Pf);
    k_phaseB_valu<<<dim3(256), dim3(256), 0, stream>>>(x_r, flag, Pf, aspect, opinion);
    k_phaseC_valu<<<dim3(1024), dim3(192), 0, stream>>>(aspect, opinion, Wtf, zr_a, zr_o, xh_a, xh_o);
    k_scan<<<dim3(128), dim3(384), 0, stream>>>(zr_a, zr_o, xh_a, xh_o, Ra, Ro, flag, out, layer);
    if (layer == 0) {
      k_score<<<dim3(32768), dim3(256), 0, stream>>>(out, va, vo, flag, scores);
      k_softmax<<<dim3(128), dim3(256), 0, stream>>>(scores);
      k_ctx_m<<<dim3(128), dim3(256), 0, stream>>>(scores, x_r, Ma, Mo, flag, ma_ws, mo_ws);
    }
  }
}

// Round 5
// 4128.763 us; speedup vs baseline: 2.1396x; 2.1396x over previous
//
#include <hip/hip_runtime.h>
#include <hip/hip_bf16.h>
#include <math.h>

#define B_  64
#define T_  1024
#define H_  256
#define K_  64
#define U_  128
#define U3_ 384

typedef unsigned short ushort_t;
typedef __attribute__((ext_vector_type(8))) short short8;
typedef __attribute__((ext_vector_type(8))) _Float16 half8;
typedef __attribute__((ext_vector_type(4))) float floatx4;

__device__ __forceinline__ float bf2f(ushort_t v) {
  unsigned int u = ((unsigned int)v) << 16;
  return __builtin_bit_cast(float, u);
}
__device__ __forceinline__ float h2f(ushort_t v) {
  return (float)__builtin_bit_cast(_Float16, v);
}
__device__ __forceinline__ ushort_t f2h(float f) {
  return __builtin_bit_cast(ushort_t, (_Float16)f);
}
// load element i from a buffer that is f32 (isf=1) or bf16 (isf=0)
__device__ __forceinline__ float ldf(const void* p, size_t i, int isf) {
  return isf ? ((const float*)p)[i] : bf2f(((const ushort_t*)p)[i]);
}

// ------------------------------------------------ dtype sniff: flag=1 if inputs are f32
__global__ void k_sniff(const ushort_t* __restrict__ xr, int* __restrict__ flag) {
  __shared__ int red[256];
  int tx = threadIdx.x;
  int hits = 0;
  for (int i = 0; i < 64; ++i) {
    ushort_t w = xr[tx + i * 256];
    int e = (w >> 7) & 0xff;
    hits += (e >= 0x70 && e <= 0x82) ? 1 : 0;
  }
  red[tx] = hits;
  __syncthreads();
  for (int off = 128; off > 0; off >>= 1) {
    if (tx < off) red[tx] += red[tx + off];
    __syncthreads();
  }
  if (tx == 0) flag[0] = (red[0] < 12288) ? 1 : 0;
}

// ------------------------------------------------ canonicalize x to f16 arena
__global__ __launch_bounds__(256) void k_canon_x(const void* __restrict__ xr,
                                                 const int* __restrict__ flag,
                                                 ushort_t* __restrict__ x16) {
  int tid = blockIdx.x * 256 + threadIdx.x;  // 2,097,152 threads, 8 elem each
  float v[8];
  if (*flag) {
    const float4* xf = (const float4*)xr;
    float4 a = xf[tid * 2], b = xf[tid * 2 + 1];
    v[0] = a.x; v[1] = a.y; v[2] = a.z; v[3] = a.w;
    v[4] = b.x; v[5] = b.y; v[6] = b.z; v[7] = b.w;
  } else {
    uint4 raw = ((const uint4*)xr)[tid];
    v[0] = bf2f((ushort_t)(raw.x & 0xffff)); v[1] = bf2f((ushort_t)(raw.x >> 16));
    v[2] = bf2f((ushort_t)(raw.y & 0xffff)); v[3] = bf2f((ushort_t)(raw.y >> 16));
    v[4] = bf2f((ushort_t)(raw.z & 0xffff)); v[5] = bf2f((ushort_t)(raw.z >> 16));
    v[6] = bf2f((ushort_t)(raw.w & 0xffff)); v[7] = bf2f((ushort_t)(raw.w >> 16));
  }
  uint4 o;
  o.x = (unsigned)f2h(v[0]) | ((unsigned)f2h(v[1]) << 16);
  o.y = (unsigned)f2h(v[2]) | ((unsigned)f2h(v[3]) << 16);
  o.z = (unsigned)f2h(v[4]) | ((unsigned)f2h(v[5]) << 16);
  o.w = (unsigned)f2h(v[6]) | ((unsigned)f2h(v[7]) << 16);
  ((uint4*)x16)[tid] = o;
}

// ------------------------------------------------ init m state
__global__ void k_init_m(const void* __restrict__ m0a, const void* __restrict__ m0o,
                         const int* __restrict__ flag,
                         float* __restrict__ ma_ws, float* __restrict__ mo_ws) {
  int b = blockIdx.x, tx = threadIdx.x, isf = *flag;
  ma_ws[b * H_ + tx] = ldf(m0a, tx, isf);
  mo_ws[b * H_ + tx] = ldf(m0o, tx, isf);
}

// ------------------------------------------------ Wt16[g][j][u] = W_g[u][j]  (f16)
__global__ void k_transpose(const void* __restrict__ Wa, const void* __restrict__ Wo,
                            const int* __restrict__ flag, ushort_t* __restrict__ Wt16) {
  int bx = blockIdx.x, isf = *flag;
  int g = bx / 192;
  int i = (bx % 192) * 256 + threadIdx.x;  // i = j*128 + u
  const void* W = g ? Wo : Wa;
  int jj = i >> 7, u = i & 127;
  Wt16[(size_t)g * (U3_ * U_) + i] = f2h(ldf(W, u * U3_ + jj, isf));
}

// ------------------------------------------------ Phase A: P16[b, g*64+k, h] = sum_j U[k,h,j] m[b,j]
__global__ __launch_bounds__(256) void k_phaseA(
    const void* __restrict__ Ua, const void* __restrict__ Va,
    const void* __restrict__ Uo, const void* __restrict__ Vo,
    const int* __restrict__ flag,
    const float* __restrict__ ma_ws, const float* __restrict__ mo_ws,
    ushort_t* __restrict__ P16) {
  int gk = blockIdx.x;
  int g = gk >> 6, k = gk & 63;
  const void* U = (g == 0) ? Ua : (g == 1) ? Va : (g == 2) ? Uo : Vo;
  const float* msrc = (g & 1) ? mo_ws : ma_ws;  // Ua(ma), Va(mo), Uo(ma), Vo(mo)
  int tx = threadIdx.x;  // h
  int isf = *flag;
  __shared__ __align__(16) float m_l[64 * 128];
  float acc[64];
#pragma unroll
  for (int b = 0; b < 64; ++b) acc[b] = 0.f;
  size_t rowoff = ((size_t)k * H_ + tx) * H_;
  for (int pass = 0; pass < 2; ++pass) {
    for (int i = 0; i < 32; ++i) {
      int flat = tx + i * 256;
      m_l[flat] = msrc[(flat >> 7) * H_ + pass * 128 + (flat & 127)];
    }
    __syncthreads();
    for (int c = 0; c < 16; ++c) {
      float uv[8];
      if (isf) {
        const float* uf = (const float*)U + rowoff + pass * 128 + c * 8;
        float4 A = *(const float4*)uf;
        float4 Bv = *(const float4*)(uf + 4);
        uv[0] = A.x; uv[1] = A.y; uv[2] = A.z; uv[3] = A.w;
        uv[4] = Bv.x; uv[5] = Bv.y; uv[6] = Bv.z; uv[7] = Bv.w;
      } else {
        const ushort_t* ub = (const ushort_t*)U + rowoff + pass * 128 + c * 8;
        uint4 raw = *(const uint4*)ub;
        uv[0] = bf2f((ushort_t)(raw.x & 0xffff)); uv[1] = bf2f((ushort_t)(raw.x >> 16));
        uv[2] = bf2f((ushort_t)(raw.y & 0xffff)); uv[3] = bf2f((ushort_t)(raw.y >> 16));
        uv[4] = bf2f((ushort_t)(raw.z & 0xffff)); uv[5] = bf2f((ushort_t)(raw.z >> 16));
        uv[6] = bf2f((ushort_t)(raw.w & 0xffff)); uv[7] = bf2f((ushort_t)(raw.w >> 16));
      }
#pragma unroll
      for (int b = 0; b < 64; ++b) {
        const float* mr = &m_l[b * 128 + c * 8];
        float4 mA = *(const float4*)mr;
        float4 mB = *(const float4*)(mr + 4);
        float s = acc[b];
        s = fmaf(uv[0], mA.x, s); s = fmaf(uv[1], mA.y, s);
        s = fmaf(uv[2], mA.z, s); s = fmaf(uv[3], mA.w, s);
        s = fmaf(uv[4], mB.x, s); s = fmaf(uv[5], mB.y, s);
        s = fmaf(uv[6], mB.z, s); s = fmaf(uv[7], mB.w, s);
        acc[b] = s;
      }
    }
    __syncthreads();
  }
  size_t base = ((size_t)(g * 64 + k)) * H_ + tx;
#pragma unroll 4
  for (int b = 0; b < 64; ++b) P16[base + (size_t)b * (256 * H_)] = f2h(acc[b]);
}

// ------------------------------------------------ Phase B (MFMA f16): tanh(x[b]·P[b]^T) -> aspect/opinion (f16)
__global__ __launch_bounds__(256) void k_phaseB(
    const ushort_t* __restrict__ x16, const ushort_t* __restrict__ P16,
    ushort_t* __restrict__ aspect, ushort_t* __restrict__ opinion) {
  int wave = threadIdx.x >> 6;
  int lane = threadIdx.x & 63;
  int bx = blockIdx.x;  // 16384 blocks
  int b = bx >> 8;
  int rem = bx & 255;
  int tt = rem >> 2;                    // t-tile (16 rows)
  int ntile = ((rem & 3) << 2) | wave;  // 0..15
  int m = lane & 15, q = lane >> 4;
  const ushort_t* arow = x16 + ((size_t)(b * T_ + tt * 16 + m)) * H_ + q * 8;
  const ushort_t* brow = P16 + ((size_t)(b * 256 + ntile * 16 + m)) * H_ + q * 8;
  floatx4 acc = {0.f, 0.f, 0.f, 0.f};
#pragma unroll
  for (int k0 = 0; k0 < H_; k0 += 32) {
    half8 af = __builtin_bit_cast(half8, *(const short8*)(arow + k0));
    half8 bf = __builtin_bit_cast(half8, *(const short8*)(brow + k0));
    acc = __builtin_amdgcn_mfma_f32_16x16x32_f16(af, bf, acc, 0, 0, 0);
  }
  int n = ntile * 16 + m;
  ushort_t* dst;
  int nn;
  if (n < 128) { dst = aspect; nn = n; } else { dst = opinion; nn = n - 128; }
#pragma unroll
  for (int i = 0; i < 4; ++i) {
    int t = tt * 16 + q * 4 + i;
    dst[((size_t)(b * T_ + t)) * U_ + nn] = f2h(tanhf(acc[i]));
  }
}

// ------------------------------------------------ Phase C (MFMA f16): xw = seq @ W; cols 0..255 -> zr, 256..383 -> xh
__global__ __launch_bounds__(256) void k_phaseC(
    const ushort_t* __restrict__ aspect, const ushort_t* __restrict__ opinion,
    const ushort_t* __restrict__ Wt16,
    ushort_t* __restrict__ zr_a, ushort_t* __restrict__ zr_o,
    ushort_t* __restrict__ xh_a, ushort_t* __restrict__ xh_o) {
  int g = blockIdx.y;
  const ushort_t* A = g ? opinion : aspect;
  const ushort_t* Bm = Wt16 + (size_t)g * (U3_ * U_);
  ushort_t* ZR = g ? zr_o : zr_a;
  ushort_t* XH = g ? xh_o : xh_a;
  int id = blockIdx.x * 4 + (threadIdx.x >> 6);  // [0, 98304)
  int mt = id / 24, nt = id % 24;
  int lane = threadIdx.x & 63;
  int m = lane & 15, q = lane >> 4;
  const ushort_t* arow = A + ((size_t)(mt * 16 + m)) * U_ + q * 8;
  const ushort_t* brow = Bm + ((size_t)(nt * 16 + m)) * U_ + q * 8;
  floatx4 acc = {0.f, 0.f, 0.f, 0.f};
#pragma unroll
  for (int k0 = 0; k0 < U_; k0 += 32) {
    half8 af = __builtin_bit_cast(half8, *(const short8*)(arow + k0));
    half8 bf = __builtin_bit_cast(half8, *(const short8*)(brow + k0));
    acc = __builtin_amdgcn_mfma_f32_16x16x32_f16(af, bf, acc, 0, 0, 0);
  }
  int col = nt * 16 + m;
  if (nt < 16) {  // z|r columns
#pragma unroll
    for (int i = 0; i < 4; ++i) {
      int row = mt * 16 + q * 4 + i;
      ZR[(size_t)row * 256 + col] = f2h(acc[i]);
    }
  } else {        // h columns
#pragma unroll
    for (int i = 0; i < 4; ++i) {
      int row = mt * 16 + q * 4 + i;
      XH[(size_t)row * U_ + (col - 256)] = f2h(acc[i]);
    }
  }
}

// ------------------------------------------------ GRU scan (f16 inputs, f32 state/out), software-pipelined
__global__ __launch_bounds__(384) void k_scan(const ushort_t* __restrict__ zr_a,
                                              const ushort_t* __restrict__ zr_o,
                                              const ushort_t* __restrict__ xh_a,
                                              const ushort_t* __restrict__ xh_o,
                                              const void* __restrict__ Ra,
                                              const void* __restrict__ Ro,
                                              const int* __restrict__ flag,
                                              float* __restrict__ out, int layer) {
  int g = blockIdx.x >> 6;
  int b = blockIdx.x & 63;
  const ushort_t* zr = (g ? zr_o : zr_a) + (size_t)b * T_ * 256;
  const ushort_t* xh = (g ? xh_o : xh_a) + (size_t)b * T_ * U_;
  const void* R = g ? Ro : Ra;
  float* op = out + ((size_t)g * B_ * T_ + (size_t)b * T_) * U_;
  int j = threadIdx.x;
  float r_reg[128];
  if (*flag) {
    const float* Rf = (const float*)R;
#pragma unroll
    for (int u = 0; u < 128; ++u) r_reg[u] = Rf[u * U3_ + j];
  } else {
    const ushort_t* Rb = (const ushort_t*)R;
#pragma unroll
    for (int u = 0; u < 128; ++u) r_reg[u] = bf2f(Rb[u * U3_ + j]);
  }
  __shared__ __align__(16) float h_lds[128];
  __shared__ float pre[384];
  __shared__ float xb[384];
  if (j < U_) h_lds[j] = 0.f;
  // prefetch t=0
  float cur = (j < 256) ? h2f(zr[j]) : h2f(xh[j - 256]);
  float oldc = (layer && j < U_) ? op[j] : 0.f;
  __syncthreads();
  for (int t = 0; t < T_; ++t) {
    float nxt = 0.f, oldn = 0.f;
    if (t < T_ - 1) {  // issue next step's loads; the dot hides their latency
      nxt = (j < 256) ? h2f(zr[(size_t)(t + 1) * 256 + j])
                      : h2f(xh[(size_t)(t + 1) * U_ + (j - 256)]);
      if (layer && j < U_) oldn = op[(size_t)(t + 1) * U_ + j];
    }
    float a0 = 0.f, a1 = 0.f, a2 = 0.f, a3 = 0.f;
#pragma unroll
    for (int c = 0; c < 32; ++c) {
      float4 h4 = ((const float4*)h_lds)[c];
      a0 = fmaf(h4.x, r_reg[4 * c + 0], a0);
      a1 = fmaf(h4.y, r_reg[4 * c + 1], a1);
      a2 = fmaf(h4.z, r_reg[4 * c + 2], a2);
      a3 = fmaf(h4.w, r_reg[4 * c + 3], a3);
    }
    pre[j] = (a0 + a1) + (a2 + a3);
    xb[j] = cur;
    __syncthreads();
    if (j < U_) {
      float xz = xb[j], xr = xb[j + 128], xhv = xb[j + 256];
      float z = 1.f / (1.f + __expf(-(xz + pre[j])));
      float r = 1.f / (1.f + __expf(-(xr + pre[j + U_])));
      float hh = tanhf(fmaf(r, pre[j + 2 * U_], xhv));
      float hn = z * h_lds[j] + (1.f - z) * hh;
      op[(size_t)t * U_ + j] = layer ? (oldc + hn) : hn;
      h_lds[j] = hn;
    }
    __syncthreads();
    cur = nxt;
    oldc = oldn;
  }
}

// ------------------------------------------------ scores[g,b,t] = ra[b,t,:]·v
__global__ void k_score(const float* __restrict__ out, const void* __restrict__ va,
                        const void* __restrict__ vo, const int* __restrict__ flag,
                        float* __restrict__ scores) {
  int wave = threadIdx.x >> 6, lane = threadIdx.x & 63;
  int pair = blockIdx.x * 4 + wave;  // [0, 131072)
  int g = pair >> 16;
  int bt = pair & 65535;
  int isf = *flag;
  const void* v = g ? vo : va;
  const float* o = out + ((size_t)g * (B_ * T_) + bt) * U_ + lane * 2;
  float s = o[0] * ldf(v, lane * 2, isf) + o[1] * ldf(v, lane * 2 + 1, isf);
#pragma unroll
  for (int off = 32; off > 0; off >>= 1) s += __shfl_down(s, off, 64);
  if (lane == 0) scores[pair] = s;
}

// ------------------------------------------------ softmax over T, in place
__global__ void k_softmax(float* __restrict__ scores) {
  int row = blockIdx.x;
  float* s = scores + (size_t)row * T_;
  int tx = threadIdx.x;
  __shared__ float red[256];
  float v[4];
  float mx = -1e30f;
#pragma unroll
  for (int i = 0; i < 4; ++i) { v[i] = s[tx + i * 256]; mx = fmaxf(mx, v[i]); }
  red[tx] = mx;
  __syncthreads();
  for (int off = 128; off > 0; off >>= 1) {
    if (tx < off) red[tx] = fmaxf(red[tx], red[tx + off]);
    __syncthreads();
  }
  float M = red[0];
  __syncthreads();
  float sm = 0.f;
#pragma unroll
  for (int i = 0; i < 4; ++i) { v[i] = expf(v[i] - M); sm += v[i]; }
  red[tx] = sm;
  __syncthreads();
  for (int off = 128; off > 0; off >>= 1) {
    if (tx < off) red[tx] += red[tx + off];
    __syncthreads();
  }
  float inv = 1.f / red[0];
#pragma unroll
  for (int i = 0; i < 4; ++i) s[tx + i * 256] = v[i] * inv;
}

// ------------------------------------------------ m = tanh(m@M) + alpha^T x
__global__ void k_ctx_m(const float* __restrict__ alpha, const void* __restrict__ x,
                        const void* __restrict__ Ma, const void* __restrict__ Mo,
                        const int* __restrict__ flag,
                        float* __restrict__ ma_ws, float* __restrict__ mo_ws) {
  int g = blockIdx.x >> 6, b = blockIdx.x & 63;
  int isf = *flag;
  const float* al = alpha + ((size_t)g * B_ + b) * T_;
  const void* Mm = g ? Mo : Ma;
  float* m_ws = g ? mo_ws : ma_ws;
  int tx = threadIdx.x;  // h
  __shared__ float a_l[1024];
  __shared__ float m_l[256];
#pragma unroll
  for (int i = 0; i < 4; ++i) a_l[tx + i * 256] = al[tx + i * 256];
  m_l[tx] = m_ws[b * H_ + tx];
  __syncthreads();
  float acc = 0.f;
  for (int t = 0; t < T_; ++t)
    acc = fmaf(a_l[t], ldf(x, (size_t)(b * T_ + t) * H_ + tx, isf), acc);
  float acc2 = 0.f;
  for (int jj = 0; jj < 256; ++jj) acc2 = fmaf(m_l[jj], ldf(Mm, jj * 256 + tx, isf), acc2);
  m_ws[b * H_ + tx] = tanhf(acc2) + acc;
}

// ------------------------------------------------ launch
extern "C" void kernel_launch(void* const* d_in, const int* in_sizes, int n_in,
                              void* d_out, int out_size, void* d_ws, size_t ws_size,
                              hipStream_t stream) {
  const void* x_r = d_in[0];
  const void* m0a = d_in[1];
  const void* m0o = d_in[2];
  const void* Ua  = d_in[3];
  const void* Uo  = d_in[4];
  const void* Va  = d_in[5];
  const void* Vo  = d_in[6];
  const void* Ma  = d_in[7];
  const void* Mo  = d_in[8];
  const void* va  = d_in[9];
  const void* vo  = d_in[10];
  const void* Wa  = d_in[11];
  const void* Ra  = d_in[12];
  const void* Wo  = d_in[13];
  const void* Ro  = d_in[14];
  float* out = (float*)d_out;  // reference output dtype = float32

  char* ws = (char*)d_ws;
  int*      flag    = (int*)(ws + 0);                // 1 KB pad
  float*    ma_ws   = (float*)(ws + 1024);           // 64 KB
  float*    mo_ws   = (float*)(ws + 66560);          // 64 KB
  ushort_t* Wt16    = (ushort_t*)(ws + 132096);      // 192 KB [2,384,128] f16
  ushort_t* x16     = (ushort_t*)(ws + 328704);      // 32 MB  [64,1024,256] f16
  ushort_t* P16     = (ushort_t*)(ws + 33883136);    // 8 MB   [64,256,256] f16
  float*    scores  = (float*)(ws + 33883136);       // ALIAS: P16 dead while scores live
  ushort_t* aspect  = (ushort_t*)(ws + 42271744);    // 16 MB  [64,1024,128] f16
  ushort_t* opinion = (ushort_t*)(ws + 59048960);    // 16 MB
  ushort_t* zr_a    = (ushort_t*)(ws + 75826176);    // 32 MB  [64,1024,256] f16
  ushort_t* zr_o    = (ushort_t*)(ws + 109380608);   // 32 MB
  ushort_t* xh_a    = (ushort_t*)(ws + 142935040);   // 16 MB  [64,1024,128] f16
  ushort_t* xh_o    = (ushort_t*)(ws + 159712256);   // 16 MB -> total 176,489,472 B

  if (ws_size < 176489472ULL) return;  // tripwire: zero output (err ~1.96) => ws too small

  k_sniff<<<dim3(1), dim3(256), 0, stream>>>((const ushort_t*)x_r, flag);
  k_canon_x<<<dim3(8192), dim3(256), 0, stream>>>(x_r, flag, x16);
  k_init_m<<<dim3(64), dim3(256), 0, stream>>>(m0a, m0o, flag, ma_ws, mo_ws);
  k_transpose<<<dim3(384), dim3(256), 0, stream>>>(Wa, Wo, flag, Wt16);

  for (int layer = 0; layer < 2; ++layer) {
    k_phaseA<<<dim3(256), dim3(256), 0, stream>>>(Ua, Va, Uo, Vo, flag, ma_ws, mo_ws, P16);
    k_phaseB<<<dim3(16384), dim3(256), 0, stream>>>(x16, P16, aspect, opinion);
    k_phaseC<<<dim3(24576, 2), dim3(256), 0, stream>>>(aspect, opinion, Wt16, zr_a, zr_o, xh_a, xh_o);
    k_scan<<<dim3(128), dim3(384), 0, stream>>>(zr_a, zr_o, xh_a, xh_o, Ra, Ro, flag, out, layer);
    if (layer == 0) {
      k_score<<<dim3(32768), dim3(256), 0, stream>>>(out, va, vo, flag, scores);
      k_softmax<<<dim3(128), dim3(256), 0, stream>>>(scores);
      k_ctx_m<<<dim3(128), dim3(256), 0, stream>>>(scores, x_r, Ma, Mo, flag, ma_ws, mo_ws);
    }
  }
}